// Round 7
// baseline (314.071 us; speedup 1.0000x reference)
//
#include <hip/hip_runtime.h>

#define B_ 8
#define S_ 1024
#define D_ 1024
#define H_ 16
#define DK_ 64
#define M_ (B_ * S_)
#define NEGINF -1e38f

typedef __bf16 bf16_t;
typedef __bf16 bf16x8 __attribute__((ext_vector_type(8)));
typedef float f32x4 __attribute__((ext_vector_type(4)));
typedef unsigned int u32;

__device__ inline f32x4 mfma_bf16(bf16x8 a, bf16x8 b, f32x4 c) {
    return __builtin_amdgcn_mfma_f32_16x16x32_bf16(a, b, c, 0, 0, 0);
}

// Async global->LDS, 16B per lane. LDS dest = (wave-uniform base) + lane*16B.
typedef const __attribute__((address_space(1))) u32* gas1_t;
typedef __attribute__((address_space(3))) u32* las3_t;
__device__ inline void gl_lds16(const void* g, void* l) {
    __builtin_amdgcn_global_load_lds((gas1_t)g, (las3_t)l, 16, 0, 0);
}

// 8 contiguous elements -> bf16x8 (converting when source is fp32).
__device__ inline bf16x8 load8(const bf16_t* p) { return *(const bf16x8*)p; }
__device__ inline bf16x8 load8(const float* p) {
    const f32x4 a = *(const f32x4*)p;
    const f32x4 b = *(const f32x4*)(p + 4);
    bf16x8 r;
    r[0] = (bf16_t)a[0]; r[1] = (bf16_t)a[1];
    r[2] = (bf16_t)a[2]; r[3] = (bf16_t)a[3];
    r[4] = (bf16_t)b[0]; r[5] = (bf16_t)b[1];
    r[6] = (bf16_t)b[2]; r[7] = (bf16_t)b[3];
    return r;
}
__device__ inline void store_elem(bf16_t* Y, size_t i, float v) { Y[i] = (bf16_t)v; }
__device__ inline void store_elem(float* Y, size_t i, float v) { Y[i] = v; }

// ---------------------------------------------------------------------------
// FUSED prep: z=0..3 transpose+convert weight matrix z (fp32 [K,N] -> bf16
// [N,K]); z=4..6 bulk-convert activation z-4 (query/key/value) to bf16.
// ---------------------------------------------------------------------------
__global__ __launch_bounds__(256) void prep(
    const float* __restrict__ wq, const float* __restrict__ wk,
    const float* __restrict__ wv, const float* __restrict__ wo,
    bf16_t* __restrict__ wt,  // 4 contiguous [D,D] outputs
    const float* __restrict__ q, const float* __restrict__ k,
    const float* __restrict__ v,
    bf16_t* __restrict__ X,  // 3 contiguous [M,D] outputs
    int n8) {
    const int z = blockIdx.z;
    const int tid = threadIdx.x;
    __shared__ __align__(16) bf16_t t[32][33];
    if (z < 4) {
        if (blockIdx.x >= 1024) return;
        const float* ins[4] = {wq, wk, wv, wo};
        const float* in = ins[z];
        bf16_t* out = wt + (size_t)z * D_ * D_;
        const int n0 = (blockIdx.x & 31) * 32, k0 = ((int)blockIdx.x >> 5) * 32;
        const int tx = tid & 31, ty = tid >> 5;
        for (int i = ty; i < 32; i += 8)
            t[i][tx] = (bf16_t)in[(size_t)(k0 + i) * D_ + n0 + tx];
        __syncthreads();
        for (int i = ty; i < 32; i += 8)
            out[(size_t)(n0 + i) * D_ + k0 + tx] = t[tx][i];
    } else {
        const float* ins[3] = {q, k, v};
        const float* in = ins[z - 4];
        bf16_t* out = X + (size_t)(z - 4) * M_ * D_;
        const int i = blockIdx.x * 256 + tid;
        if (i < n8) *(bf16x8*)(out + (size_t)i * 8) = load8(in + (size_t)i * 8);
    }
}

// fp32 -> bf16 bulk convert, one matrix (fallback path).
__global__ __launch_bounds__(256) void cvt_bf16(const float* __restrict__ in,
                                                bf16_t* __restrict__ out,
                                                int n8) {
    const int i = blockIdx.x * 256 + threadIdx.x;
    if (i < n8) *(bf16x8*)(out + (size_t)i * 8) = load8(in + (size_t)i * 8);
}

// ---------------------------------------------------------------------------
// GEMM core: C[128,128] tile, 4 waves, BK=32 (m97-proven geometry: 16 MFMA +
// 8 ds_read_b128 per K-iter), 2-phase double-buffer (stage t+1 before
// compute t, one barrier per iter). LDS = 32 KB -> 4-5 blocks/CU (r6's BK=64
// used 64 KB -> 2 blocks/CU, Occupancy 20%, 548 TF). Cross-block TLP now
// hides the per-block barrier drains (m114 mechanism).
// LDS chunk XOR-swizzle: slot s of row r holds global chunk s^(r&3), applied
// on the GLOBAL source (rule #21); gl_lds dest stays linear; fragment
// ds_read_b128 slot = (quad^(ln&3)) -> <=2-way bank aliasing (free).
// ---------------------------------------------------------------------------
template <typename TX>
__device__ inline void gemm_core(const TX* __restrict__ X,
                                 const bf16_t* __restrict__ Wt, int m0, int n0,
                                 bf16_t (*As)[128 * 32], bf16_t (*Bs)[128 * 32],
                                 f32x4 acc[4][4]) {
    const int tid = threadIdx.x;
    const int lane = tid & 63, wave = tid >> 6;
    const int ln = lane & 15, quad = lane >> 4;
    const int wm = (wave & 1) * 64, wn = (wave >> 1) * 64;

    // staging: per call a wave covers 16 rows (lane>>2) x 4 chunks (lane&3)
    const int sr = lane >> 2;        // row within 16-row group
    const int sch = lane & 3;        // LDS chunk slot this lane fills
    const int swc = sch ^ (sr & 3);  // global chunk belonging in slot sch

    auto stage = [&](int d, int k0) {
#pragma unroll
        for (int i = 0; i < 2; i++) {
            const int row = i * 64 + wave * 16 + sr;
            if constexpr (sizeof(TX) == 2) {
                gl_lds16(X + (size_t)(m0 + row) * D_ + k0 + swc * 8,
                         As[d] + i * 2048 + wave * 512);
            } else {
                *(bf16x8*)(As[d] + row * 32 + sch * 8) =
                    load8(X + (size_t)(m0 + row) * D_ + k0 + swc * 8);
            }
            gl_lds16(Wt + (size_t)(n0 + row) * D_ + k0 + swc * 8,
                     Bs[d] + i * 2048 + wave * 512);
        }
    };

    stage(0, 0);
    __syncthreads();

    int cur = 0;
    for (int t = 0; t < 32; ++t) {
        if (t < 31) stage(cur ^ 1, (t + 1) * 32);  // async, drains at barrier
        bf16x8 af[4], bfr[4];
        const int slot = (quad ^ (ln & 3)) * 8;
#pragma unroll
        for (int mt = 0; mt < 4; mt++)
            af[mt] =
                *(const bf16x8*)(As[cur] + (wm + mt * 16 + ln) * 32 + slot);
#pragma unroll
        for (int nt = 0; nt < 4; nt++)
            bfr[nt] =
                *(const bf16x8*)(Bs[cur] + (wn + nt * 16 + ln) * 32 + slot);
#pragma unroll
        for (int mt = 0; mt < 4; mt++)
#pragma unroll
            for (int nt = 0; nt < 4; nt++)
                acc[mt][nt] = mfma_bf16(af[mt], bfr[nt], acc[mt][nt]);
        __syncthreads();  // vmcnt(0)+lgkmcnt(0)+barrier: next buf ready
        cur ^= 1;
    }
}

// ---------------------------------------------------------------------------
// FUSED Q/K/V projection: one dispatch, grid (M/128, D/128, 3). z selects
// input X slab, weight slab, bias, scale, and store layout (z<2: [B,H,S,DK];
// z==2: [B,H,DK,S]). Linear id = x + 64y + 512z -> XCD = x&7: the 8 blocks
// sharing an A-panel sit on one XCD (panel L2-resident, B whole = 2MB).
// ---------------------------------------------------------------------------
__global__ __launch_bounds__(256) void gemm_qkv(
    const bf16_t* __restrict__ Xbase, const bf16_t* __restrict__ Wtbase,
    const float* __restrict__ bq, const float* __restrict__ bk,
    const float* __restrict__ bv, bf16_t* __restrict__ Ybase, float qscale) {
    __shared__ __align__(16) bf16_t As[2][128 * 32];
    __shared__ __align__(16) bf16_t Bs[2][128 * 32];
    const int z = blockIdx.z;
    const bf16_t* X = Xbase + (size_t)z * M_ * D_;
    const bf16_t* Wt = Wtbase + (size_t)z * D_ * D_;
    const float* bias = z == 0 ? bq : (z == 1 ? bk : bv);
    bf16_t* Y = Ybase + (size_t)z * M_ * D_;
    const float scale = z == 0 ? qscale : 1.0f;
    const int m0 = blockIdx.x * 128, n0 = blockIdx.y * 128;

    f32x4 acc[4][4] = {};
    gemm_core(X, Wt, m0, n0, As, Bs, acc);

    const int tid = threadIdx.x;
    const int lane = tid & 63, wave = tid >> 6;
    const int ln = lane & 15, quad = lane >> 4;
    const int wm = (wave & 1) * 64, wn = (wave >> 1) * 64;
#pragma unroll
    for (int mt = 0; mt < 4; mt++)
#pragma unroll
        for (int nt = 0; nt < 4; nt++)
#pragma unroll
            for (int r = 0; r < 4; r++) {
                const int m = m0 + wm + mt * 16 + quad * 4 + r;
                const int n = n0 + wn + nt * 16 + ln;
                const float v = (acc[mt][nt][r] + bias[n]) * scale;
                const int b = m >> 10, s = m & 1023;
                const int h = n >> 6, d = n & 63;
                const size_t idx =
                    (z == 2) ? ((size_t)(b * H_ + h) * DK_ + d) * S_ + s
                             : ((size_t)(b * H_ + h) * S_ + s) * DK_ + d;
                Y[idx] = (bf16_t)v;
            }
}

// ---------------------------------------------------------------------------
// Single GEMM (output projection + fallback path).
// MODE 0: Y fp32 row-major [M,N];  MODE 1: bf16 [B,H,S,DK];  MODE 2: bf16
// [B,H,DK,S]. Grid (M/128, N/128): x=m-panel -> XCD L2 locality.
// ---------------------------------------------------------------------------
template <int MODE, typename TX, typename TY>
__global__ __launch_bounds__(256) void gemm_bt(
    const TX* __restrict__ X, const bf16_t* __restrict__ Wt,
    const float* __restrict__ bias, TY* __restrict__ Y, float scale) {
    __shared__ __align__(16) bf16_t As[2][128 * 32];
    __shared__ __align__(16) bf16_t Bs[2][128 * 32];
    const int m0 = blockIdx.x * 128, n0 = blockIdx.y * 128;

    f32x4 acc[4][4] = {};
    gemm_core(X, Wt, m0, n0, As, Bs, acc);

    const int tid = threadIdx.x;
    const int lane = tid & 63, wave = tid >> 6;
    const int ln = lane & 15, quad = lane >> 4;
    const int wm = (wave & 1) * 64, wn = (wave >> 1) * 64;
#pragma unroll
    for (int mt = 0; mt < 4; mt++)
#pragma unroll
        for (int nt = 0; nt < 4; nt++)
#pragma unroll
            for (int r = 0; r < 4; r++) {
                const int m = m0 + wm + mt * 16 + quad * 4 + r;
                const int n = n0 + wn + nt * 16 + ln;
                const float v = (acc[mt][nt][r] + bias[n]) * scale;
                size_t idx;
                if (MODE == 0) {
                    idx = (size_t)m * D_ + n;
                } else {
                    const int b = m >> 10, s = m & 1023;
                    const int h = n >> 6, d = n & 63;
                    if (MODE == 1)
                        idx = ((size_t)(b * H_ + h) * S_ + s) * DK_ + d;
                    else
                        idx = ((size_t)(b * H_ + h) * DK_ + d) * S_ + s;
                }
                store_elem(Y, idx, v);
            }
}

// ---------------------------------------------------------------------------
// Causal flash attention (r4-proven version, <=40us): FIXED-max exp2-domain
// softmax, P IN REGISTERS via swapped-operand QK^T. Single-buffered K/V
// staging (16KB LDS) - the r5 double-buffer REGRESSED this kernel (50 vs
// <=40us) and was reverted. K rows PERMUTED at staging (bit-shuffle on the
// per-lane GLOBAL source row; LDS dest linear, rule #21) so S^T output
// positions coincide with the PV A-fragment layout: position p=nt*16+quad*4+r
// holds true k = (nt&1)*32 + quad*8 + (nt>>1)*4 + r. P->PV repack is a pure
// in-register bf16 cast (no LDS, no cross-lane). Rowsum via MFMA with ones.
// Grid (bh, chunk): same-bh blocks -> same XCD (K/V L2-resident);
// launch_bounds(256,4). Q,K: [B*H,S,DK]  Vt: [B*H,DK,S]  ctx: [B,S,D] bf16.
// ---------------------------------------------------------------------------
__global__ __launch_bounds__(256, 4) void MaskedMultiHeadAttention_90709709291709_kernel(
    const bf16_t* __restrict__ Q, const bf16_t* __restrict__ K,
    const bf16_t* __restrict__ Vt, bf16_t* __restrict__ ctx) {
    __shared__ __align__(16) bf16_t Ks[64 * 64];
    __shared__ __align__(16) bf16_t Vs[64 * 64];

    const int bh = blockIdx.x;
    const int j = 7 - (int)blockIdx.y;  // heavy chunks dispatched first
    const int tid = threadIdx.x;
    const int lane = tid & 63, wave = tid >> 6;
    const int ln = lane & 15, quad = lane >> 4;

    const bf16_t* Qb = Q + (size_t)bh * S_ * DK_;
    const bf16_t* Kb = K + (size_t)bh * S_ * DK_;
    const bf16_t* Vb = Vt + (size_t)bh * DK_ * S_;
    const int b = bh >> 4, h = bh & 15;

    bf16x8 ones8;
#pragma unroll
    for (int i = 0; i < 8; i++) ones8[i] = (bf16_t)1.0f;

    const int qb = j * 128;
    const int wq = qb + wave * 32;

    bf16x8 qf[2][2];
#pragma unroll
    for (int mi = 0; mi < 2; mi++)
#pragma unroll
        for (int kk = 0; kk < 2; kk++)
            qf[mi][kk] = *(const bf16x8*)(
                Qb + (size_t)(wq + mi * 16 + ln) * DK_ + kk * 32 + quad * 8);

    f32x4 o[2][4] = {};
    f32x4 ol[2] = {};

    // staging geometry: each gl_lds16 covers 8 rows x 64B
    const int r8 = lane >> 3;        // row-in-group 0..7
    const int sc = (lane & 7) ^ r8;  // pre-swizzled source chunk (key = row&7)

    const int kend = qb + 128;
    for (int kt = 0; kt < kend; kt += 64) {
        // ---- cooperative staging; K rows bit-shuffle-permuted at source ----
#pragma unroll
        for (int i = 0; i < 2; i++) {
            const int g = wave * 2 + i;  // 8-row group 0..7
            // LDS position p = g*8+r8 receives K row k(p):
            // k = g1*32 + g0*16 + r8_2*8 + g2*4 + (r8&3)
            const int krow = (g & 2) * 16 + (g & 1) * 16 + (r8 & 4) * 2 +
                             (g & 4) + (r8 & 3);
            gl_lds16(Kb + (size_t)(kt + krow) * DK_ + sc * 8, Ks + g * 512);
            gl_lds16(Vb + (size_t)(g * 8 + r8) * S_ + kt + sc * 8,
                     Vs + g * 512);
        }
        __syncthreads();

        if (kt <= wq + 31) {
            bf16x8 pa[2][2];  // [mi][kk] PV A-fragments, built in-register
#pragma unroll
            for (int mi = 0; mi < 2; mi++) {
                f32x4 s[4];
#pragma unroll
                for (int nt = 0; nt < 4; nt++) {
                    const bf16_t* kp = Ks + (nt * 16 + ln) * 64;
                    const bf16x8 kf0 =
                        *(const bf16x8*)(kp + ((quad ^ (ln & 7)) * 8));
                    const bf16x8 kf1 =
                        *(const bf16x8*)(kp + (((4 + quad) ^ (ln & 7)) * 8));
                    f32x4 a = {-16.f, -16.f, -16.f, -16.f};  // exp2 shift
                    a = mfma_bf16(kf0, qf[mi][0], a);  // swapped operands
                    a = mfma_bf16(kf1, qf[mi][1], a);
                    s[nt] = a;
                }
                const int q = wq + mi * 16 + ln;  // lane's q-row (global)
                const bool needmask = (kt + 63) > q;
#pragma unroll
                for (int nt = 0; nt < 4; nt++)
#pragma unroll
                    for (int r = 0; r < 4; r++) {
                        const int ktrue = kt + (nt & 1) * 32 + quad * 8 +
                                          (nt >> 1) * 4 + r;
                        float v = s[nt][r];
                        if (needmask && ktrue > q) v = NEGINF;
                        s[nt][r] = __builtin_amdgcn_exp2f(v);
                    }
                // pack: pa[kk] elem j=2w+e <- s[2*(w>>1)+kk][2*(w&1)+e]
#pragma unroll
                for (int kk = 0; kk < 2; kk++) {
                    bf16x8 t;
#pragma unroll
                    for (int w = 0; w < 4; w++) {
                        const int nts = 2 * (w >> 1) + kk;
                        const int r0 = 2 * (w & 1);
                        t[2 * w] = (bf16_t)s[nts][r0];
                        t[2 * w + 1] = (bf16_t)s[nts][r0 + 1];
                    }
                    pa[mi][kk] = t;
                }
                ol[mi] = mfma_bf16(pa[mi][0], ones8, ol[mi]);
                ol[mi] = mfma_bf16(pa[mi][1], ones8, ol[mi]);
            }
            // ---- P * V (V fragments from LDS, shared across mi) ----
#pragma unroll
            for (int dk = 0; dk < 4; dk++) {
                const bf16_t* vp = Vs + (dk * 16 + ln) * 64;
                const bf16x8 vf0 = *(const bf16x8*)(vp + ((quad ^ (ln & 7)) * 8));
                const bf16x8 vf1 =
                    *(const bf16x8*)(vp + (((4 + quad) ^ (ln & 7)) * 8));
#pragma unroll
                for (int mi = 0; mi < 2; mi++) {
                    o[mi][dk] = mfma_bf16(pa[mi][0], vf0, o[mi][dk]);
                    o[mi][dk] = mfma_bf16(pa[mi][1], vf1, o[mi][dk]);
                }
            }
        }
        __syncthreads();  // Ks/Vs reads done before next staging pass
    }

#pragma unroll
    for (int mi = 0; mi < 2; mi++)
#pragma unroll
        for (int r = 0; r < 4; r++) {
            const float inv = 1.f / ol[mi][r];
            const int row = wq + mi * 16 + quad * 4 + r;
            const size_t base = ((size_t)b * S_ + row) * D_ + h * DK_;
#pragma unroll
            for (int dk = 0; dk < 4; dk++)
                ctx[base + dk * 16 + ln] = (bf16_t)(o[mi][dk][r] * inv);
        }
}

// Vectorized d2d copy (16B per thread).
__global__ __launch_bounds__(256) void copy16(const f32x4* __restrict__ src,
                                              f32x4* __restrict__ dst, int n4) {
    const int i = blockIdx.x * 256 + threadIdx.x;
    if (i < n4) dst[i] = src[i];
}

extern "C" void kernel_launch(void* const* d_in, const int* in_sizes, int n_in,
                              void* d_out, int out_size, void* d_ws,
                              size_t ws_size, hipStream_t stream) {
    const float* query = (const float*)d_in[0];
    const float* key = (const float*)d_in[1];
    const float* value = (const float*)d_in[2];
    const float* w_q = (const float*)d_in[4];
    const float* b_q = (const float*)d_in[5];
    const float* w_k = (const float*)d_in[6];
    const float* b_k = (const float*)d_in[7];
    const float* w_v = (const float*)d_in[8];
    const float* b_v = (const float*)d_in[9];
    const float* w_o = (const float*)d_in[10];
    const float* b_o = (const float*)d_in[11];

    bf16_t* ws = (bf16_t*)d_ws;
    const size_t M8 = (size_t)M_ * D_;  // 8M elems
    const size_t DD = (size_t)D_ * D_;  // 1M elems
    bf16_t* Qw = ws;                    // [0, 8M) (Qw,Kw,Vw contiguous)
    bf16_t* Kw = ws + M8;
    bf16_t* Vw = ws + 2 * M8;
    bf16_t* wtq = ws + 3 * M8;          // 4 contiguous [D,D] bf16
    bf16_t* wtk = wtq + DD;
    bf16_t* wtv = wtk + DD;
    bf16_t* wto = wtv + DD;

    const int n8 = (int)(M8 / 8);
    const dim3 gg(M_ / 128, D_ / 128, 1);  // x=m-panel -> XCD owns 1/8 of A
    // Q scale folds 1/sqrt(DK) AND log2(e) for the exp2-domain softmax.
    const float qscale = 0.125f * 1.4426950408889634f;

    // big-ws path (>=120 MB): Xq/Xk/Xv + Cw in ws, 4 dispatches total.
    const size_t need_big = (7 * M8 + 4 * DD) * sizeof(bf16_t);  // 120 MB
    if (ws_size >= need_big) {
        bf16_t* Xq = ws + 3 * M8 + 4 * DD;  // Xq,Xk,Xv contiguous
        bf16_t* Cw = Xq + 3 * M8;
        float* Yw = (float*)d_out;

        prep<<<dim3(4096, 1, 7), 256, 0, stream>>>(
            w_q, w_k, w_v, w_o, wtq, query, key, value, Xq, n8);
        gemm_qkv<<<dim3(M_ / 128, D_ / 128, 3), 256, 0, stream>>>(
            Xq, wtq, b_q, b_k, b_v, Qw, qscale);

        MaskedMultiHeadAttention_90709709291709_kernel<<<dim3(B_ * H_, 8, 1),
                                                         256, 0, stream>>>(
            Qw, Kw, Vw, Cw);

        gemm_bt<0><<<gg, 256, 0, stream>>>(Cw, wto, b_o, Yw, 1.0f);
    } else {
        // fallback (ws < 120 MB): Xb parks in d_out, sequential cvts.
        bf16_t* Xb = (bf16_t*)d_out;
        const size_t need_direct = (4 * M8 + 4 * DD) * sizeof(bf16_t);
        const bool direct = ws_size >= need_direct;
        bf16_t* Cw = direct ? (ws + 3 * M8 + 4 * DD) : (bf16_t*)d_out;
        float* Yw = direct ? (float*)d_out : (float*)ws;
        const dim3 gc((n8 + 255) / 256, 1, 1);

        prep<<<dim3(1024, 1, 4), 256, 0, stream>>>(
            w_q, w_k, w_v, w_o, wtq, nullptr, nullptr, nullptr, nullptr, 0);
        cvt_bf16<<<gc, 256, 0, stream>>>(query, Xb, n8);
        gemm_bt<1><<<gg, 256, 0, stream>>>(Xb, wtq, b_q, Qw, qscale);
        cvt_bf16<<<gc, 256, 0, stream>>>(key, Xb, n8);
        gemm_bt<1><<<gg, 256, 0, stream>>>(Xb, wtk, b_k, Kw, 1.0f);
        cvt_bf16<<<gc, 256, 0, stream>>>(value, Xb, n8);
        gemm_bt<2><<<gg, 256, 0, stream>>>(Xb, wtv, b_v, Vw, 1.0f);

        MaskedMultiHeadAttention_90709709291709_kernel<<<dim3(B_ * H_, 8, 1),
                                                         256, 0, stream>>>(
            Qw, Kw, Vw, Cw);

        gemm_bt<0><<<gg, 256, 0, stream>>>(Cw, wto, b_o, Yw, 1.0f);
        if (!direct) {
            const int n4 = (int)((M8 * 4) / 16);
            copy16<<<dim3((n4 + 255) / 256), 256, 0, stream>>>(
                (const f32x4*)Yw, (f32x4*)d_out, n4);
        }
    }
}

// Round 8
// 298.448 us; speedup vs baseline: 1.0523x; 1.0523x over previous
//
#include <hip/hip_runtime.h>

#define B_ 8
#define S_ 1024
#define D_ 1024
#define H_ 16
#define DK_ 64
#define M_ (B_ * S_)
#define NEGINF -1e38f

typedef __bf16 bf16_t;
typedef __bf16 bf16x8 __attribute__((ext_vector_type(8)));
typedef float f32x4 __attribute__((ext_vector_type(4)));
typedef unsigned int u32;

__device__ inline f32x4 mfma_bf16(bf16x8 a, bf16x8 b, f32x4 c) {
    return __builtin_amdgcn_mfma_f32_16x16x32_bf16(a, b, c, 0, 0, 0);
}

// Async global->LDS, 16B per lane. LDS dest = (wave-uniform base) + lane*16B.
typedef const __attribute__((address_space(1))) u32* gas1_t;
typedef __attribute__((address_space(3))) u32* las3_t;
__device__ inline void gl_lds16(const void* g, void* l) {
    __builtin_amdgcn_global_load_lds((gas1_t)g, (las3_t)l, 16, 0, 0);
}

// 8 contiguous elements -> bf16x8 (converting when source is fp32).
__device__ inline bf16x8 load8(const bf16_t* p) { return *(const bf16x8*)p; }
__device__ inline bf16x8 load8(const float* p) {
    const f32x4 a = *(const f32x4*)p;
    const f32x4 b = *(const f32x4*)(p + 4);
    bf16x8 r;
    r[0] = (bf16_t)a[0]; r[1] = (bf16_t)a[1];
    r[2] = (bf16_t)a[2]; r[3] = (bf16_t)a[3];
    r[4] = (bf16_t)b[0]; r[5] = (bf16_t)b[1];
    r[6] = (bf16_t)b[2]; r[7] = (bf16_t)b[3];
    return r;
}
__device__ inline void store_elem(bf16_t* Y, size_t i, float v) { Y[i] = (bf16_t)v; }
__device__ inline void store_elem(float* Y, size_t i, float v) { Y[i] = v; }

// ---------------------------------------------------------------------------
// FUSED prep: z=0..3 transpose+convert weight matrix z (fp32 [K,N] -> bf16
// [N,K]); z=4..6 bulk-convert activation z-4 (query/key/value) to bf16.
// ---------------------------------------------------------------------------
__global__ __launch_bounds__(256) void prep(
    const float* __restrict__ wq, const float* __restrict__ wk,
    const float* __restrict__ wv, const float* __restrict__ wo,
    bf16_t* __restrict__ wt,  // 4 contiguous [D,D] outputs
    const float* __restrict__ q, const float* __restrict__ k,
    const float* __restrict__ v,
    bf16_t* __restrict__ X,  // 3 contiguous [M,D] outputs
    int n8) {
    const int z = blockIdx.z;
    const int tid = threadIdx.x;
    __shared__ __align__(16) bf16_t t[32][33];
    if (z < 4) {
        if (blockIdx.x >= 1024) return;
        const float* ins[4] = {wq, wk, wv, wo};
        const float* in = ins[z];
        bf16_t* out = wt + (size_t)z * D_ * D_;
        const int n0 = (blockIdx.x & 31) * 32, k0 = ((int)blockIdx.x >> 5) * 32;
        const int tx = tid & 31, ty = tid >> 5;
        for (int i = ty; i < 32; i += 8)
            t[i][tx] = (bf16_t)in[(size_t)(k0 + i) * D_ + n0 + tx];
        __syncthreads();
        for (int i = ty; i < 32; i += 8)
            out[(size_t)(n0 + i) * D_ + k0 + tx] = t[tx][i];
    } else {
        const float* ins[3] = {q, k, v};
        const float* in = ins[z - 4];
        bf16_t* out = X + (size_t)(z - 4) * M_ * D_;
        const int i = blockIdx.x * 256 + tid;
        if (i < n8) *(bf16x8*)(out + (size_t)i * 8) = load8(in + (size_t)i * 8);
    }
}

// fp32 -> bf16 bulk convert, one matrix (fallback path).
__global__ __launch_bounds__(256) void cvt_bf16(const float* __restrict__ in,
                                                bf16_t* __restrict__ out,
                                                int n8) {
    const int i = blockIdx.x * 256 + threadIdx.x;
    if (i < n8) *(bf16x8*)(out + (size_t)i * 8) = load8(in + (size_t)i * 8);
}

// ---------------------------------------------------------------------------
// GEMM core: C[128,128] tile, 4 waves, BK=32, 2-phase double-buffer (stage
// t+1 before compute t, one barrier per iter). LDS 32 KB -> 5 blocks/CU.
// LDS chunk XOR-swizzle with key (row>>1)&3: slot s of row r holds global
// chunk s^((r>>1)&3), applied on the GLOBAL source (rule #21); gl_lds dest
// linear. Bank walk for a quarter-wave (lanes 0-15, fixed quad): byte%128 =
// (ln&1)*64 + ((ln>>1)&3)*16 -> 8 distinct 16B groups x 2 lanes = 2-way =
// free. (r7's key row&3 gave 4-way: lanes {0,4,8,12} same group -> 6.29M
// conflicts measured; this fixes it.)
// SWAP=true computes D^T via mfma(B,A): lane ln walks the M index -> used by
// the z==2 (V^T) epilogue to get contiguous stores instead of 2KB-stride
// scatter (64 scalar VMEM/thread).
// ---------------------------------------------------------------------------
template <bool SWAP, typename TX>
__device__ inline void gemm_core(const TX* __restrict__ X,
                                 const bf16_t* __restrict__ Wt, int m0, int n0,
                                 bf16_t (*As)[128 * 32], bf16_t (*Bs)[128 * 32],
                                 f32x4 acc[4][4]) {
    const int tid = threadIdx.x;
    const int lane = tid & 63, wave = tid >> 6;
    const int ln = lane & 15, quad = lane >> 4;
    const int wm = (wave & 1) * 64, wn = (wave >> 1) * 64;

    // staging: per call a wave covers 16 rows (lane>>2) x 4 chunks (lane&3)
    const int sr = lane >> 2;               // row within 16-row group
    const int sch = lane & 3;               // LDS chunk slot this lane fills
    const int swc = sch ^ ((sr >> 1) & 3);  // global chunk for slot sch

    auto stage = [&](int d, int k0) {
#pragma unroll
        for (int i = 0; i < 2; i++) {
            const int row = i * 64 + wave * 16 + sr;
            if constexpr (sizeof(TX) == 2) {
                gl_lds16(X + (size_t)(m0 + row) * D_ + k0 + swc * 8,
                         As[d] + i * 2048 + wave * 512);
            } else {
                *(bf16x8*)(As[d] + row * 32 + sch * 8) =
                    load8(X + (size_t)(m0 + row) * D_ + k0 + swc * 8);
            }
            gl_lds16(Wt + (size_t)(n0 + row) * D_ + k0 + swc * 8,
                     Bs[d] + i * 2048 + wave * 512);
        }
    };

    stage(0, 0);
    __syncthreads();

    int cur = 0;
    for (int t = 0; t < 32; ++t) {
        if (t < 31) stage(cur ^ 1, (t + 1) * 32);  // async, drains at barrier
        bf16x8 af[4], bfr[4];
        const int slot = (quad ^ ((ln >> 1) & 3)) * 8;
#pragma unroll
        for (int mt = 0; mt < 4; mt++)
            af[mt] =
                *(const bf16x8*)(As[cur] + (wm + mt * 16 + ln) * 32 + slot);
#pragma unroll
        for (int nt = 0; nt < 4; nt++)
            bfr[nt] =
                *(const bf16x8*)(Bs[cur] + (wn + nt * 16 + ln) * 32 + slot);
#pragma unroll
        for (int mt = 0; mt < 4; mt++)
#pragma unroll
            for (int nt = 0; nt < 4; nt++) {
                if constexpr (SWAP)
                    acc[mt][nt] = mfma_bf16(bfr[nt], af[mt], acc[mt][nt]);
                else
                    acc[mt][nt] = mfma_bf16(af[mt], bfr[nt], acc[mt][nt]);
            }
        __syncthreads();  // vmcnt(0)+lgkmcnt(0)+barrier: next buf ready
        cur ^= 1;
    }
}

// ---------------------------------------------------------------------------
// FUSED Q/K/V projection: one dispatch, grid (M/128, D/128, 3). z selects
// input X slab, weight slab, bias, scale, and store layout. z<2: [B,H,S,DK]
// (normal operand order, lane walks d -> contiguous). z==2: [B,H,DK,S] via
// SWAPPED operand order (acc = C^T, lane walks s -> contiguous 32B stores).
// Linear id = x + 64y + 512z -> XCD = x&7: the 8 blocks sharing an A-panel
// sit on one XCD.
// ---------------------------------------------------------------------------
__global__ __launch_bounds__(256) void gemm_qkv(
    const bf16_t* __restrict__ Xbase, const bf16_t* __restrict__ Wtbase,
    const float* __restrict__ bq, const float* __restrict__ bk,
    const float* __restrict__ bv, bf16_t* __restrict__ Ybase, float qscale) {
    __shared__ __align__(16) bf16_t As[2][128 * 32];
    __shared__ __align__(16) bf16_t Bs[2][128 * 32];
    const int z = blockIdx.z;
    const bf16_t* X = Xbase + (size_t)z * M_ * D_;
    const bf16_t* Wt = Wtbase + (size_t)z * D_ * D_;
    const float* bias = z == 0 ? bq : (z == 1 ? bk : bv);
    bf16_t* Y = Ybase + (size_t)z * M_ * D_;
    const float scale = z == 0 ? qscale : 1.0f;
    const int m0 = blockIdx.x * 128, n0 = blockIdx.y * 128;

    const int tid = threadIdx.x;
    const int lane = tid & 63, wave = tid >> 6;
    const int ln = lane & 15, quad = lane >> 4;
    const int wm = (wave & 1) * 64, wn = (wave >> 1) * 64;

    f32x4 acc[4][4] = {};
    if (z == 2) {
        gemm_core<true>(X, Wt, m0, n0, As, Bs, acc);
        // acc = C^T: row (quad*4+r) = n index, col (ln) = m index.
#pragma unroll
        for (int mt = 0; mt < 4; mt++)
#pragma unroll
            for (int nt = 0; nt < 4; nt++)
#pragma unroll
                for (int r = 0; r < 4; r++) {
                    const int n = n0 + wn + nt * 16 + quad * 4 + r;
                    const int m = m0 + wm + mt * 16 + ln;
                    const float v = acc[mt][nt][r] + bias[n];
                    const int b = m >> 10, s = m & 1023;
                    const int h = n >> 6, d = n & 63;
                    Y[((size_t)(b * H_ + h) * DK_ + d) * S_ + s] = (bf16_t)v;
                }
    } else {
        gemm_core<false>(X, Wt, m0, n0, As, Bs, acc);
#pragma unroll
        for (int mt = 0; mt < 4; mt++)
#pragma unroll
            for (int nt = 0; nt < 4; nt++)
#pragma unroll
                for (int r = 0; r < 4; r++) {
                    const int m = m0 + wm + mt * 16 + quad * 4 + r;
                    const int n = n0 + wn + nt * 16 + ln;
                    const float v = (acc[mt][nt][r] + bias[n]) * scale;
                    const int b = m >> 10, s = m & 1023;
                    const int h = n >> 6, d = n & 63;
                    Y[((size_t)(b * H_ + h) * S_ + s) * DK_ + d] = (bf16_t)v;
                }
    }
}

// ---------------------------------------------------------------------------
// Single GEMM (output projection + fallback path).
// MODE 0: Y fp32 row-major [M,N];  MODE 1: bf16 [B,H,S,DK];  MODE 2: bf16
// [B,H,DK,S] (swapped-operand, contiguous stores).
// Grid (M/128, N/128): x=m-panel -> XCD L2 locality.
// ---------------------------------------------------------------------------
template <int MODE, typename TX, typename TY>
__global__ __launch_bounds__(256) void gemm_bt(
    const TX* __restrict__ X, const bf16_t* __restrict__ Wt,
    const float* __restrict__ bias, TY* __restrict__ Y, float scale) {
    __shared__ __align__(16) bf16_t As[2][128 * 32];
    __shared__ __align__(16) bf16_t Bs[2][128 * 32];
    const int m0 = blockIdx.x * 128, n0 = blockIdx.y * 128;

    const int tid = threadIdx.x;
    const int lane = tid & 63, wave = tid >> 6;
    const int ln = lane & 15, quad = lane >> 4;
    const int wm = (wave & 1) * 64, wn = (wave >> 1) * 64;

    f32x4 acc[4][4] = {};
    if constexpr (MODE == 2) {
        gemm_core<true>(X, Wt, m0, n0, As, Bs, acc);
#pragma unroll
        for (int mt = 0; mt < 4; mt++)
#pragma unroll
            for (int nt = 0; nt < 4; nt++)
#pragma unroll
                for (int r = 0; r < 4; r++) {
                    const int n = n0 + wn + nt * 16 + quad * 4 + r;
                    const int m = m0 + wm + mt * 16 + ln;
                    const float v = (acc[mt][nt][r] + bias[n]) * scale;
                    const int b = m >> 10, s = m & 1023;
                    const int h = n >> 6, d = n & 63;
                    store_elem(Y, ((size_t)(b * H_ + h) * DK_ + d) * S_ + s, v);
                }
    } else {
        gemm_core<false>(X, Wt, m0, n0, As, Bs, acc);
#pragma unroll
        for (int mt = 0; mt < 4; mt++)
#pragma unroll
            for (int nt = 0; nt < 4; nt++)
#pragma unroll
                for (int r = 0; r < 4; r++) {
                    const int m = m0 + wm + mt * 16 + quad * 4 + r;
                    const int n = n0 + wn + nt * 16 + ln;
                    const float v = (acc[mt][nt][r] + bias[n]) * scale;
                    size_t idx;
                    if (MODE == 0) {
                        idx = (size_t)m * D_ + n;
                    } else {
                        const int b = m >> 10, s = m & 1023;
                        const int h = n >> 6, d = n & 63;
                        idx = ((size_t)(b * H_ + h) * S_ + s) * DK_ + d;
                    }
                    store_elem(Y, idx, v);
                }
    }
}

// ---------------------------------------------------------------------------
// Causal flash attention (r4-proven version, <=40us): FIXED-max exp2-domain
// softmax, P IN REGISTERS via swapped-operand QK^T. Single-buffered K/V
// staging (16KB LDS) - the r5 double-buffer REGRESSED this kernel (50 vs
// <=40us) and was reverted. K rows PERMUTED at staging (bit-shuffle on the
// per-lane GLOBAL source row; LDS dest linear, rule #21) so S^T output
// positions coincide with the PV A-fragment layout: position p=nt*16+quad*4+r
// holds true k = (nt&1)*32 + quad*8 + (nt>>1)*4 + r. P->PV repack is a pure
// in-register bf16 cast (no LDS, no cross-lane). Rowsum via MFMA with ones.
// Grid (bh, chunk): same-bh blocks -> same XCD (K/V L2-resident);
// launch_bounds(256,4). Q,K: [B*H,S,DK]  Vt: [B*H,DK,S]  ctx: [B,S,D] bf16.
// ---------------------------------------------------------------------------
__global__ __launch_bounds__(256, 4) void MaskedMultiHeadAttention_90709709291709_kernel(
    const bf16_t* __restrict__ Q, const bf16_t* __restrict__ K,
    const bf16_t* __restrict__ Vt, bf16_t* __restrict__ ctx) {
    __shared__ __align__(16) bf16_t Ks[64 * 64];
    __shared__ __align__(16) bf16_t Vs[64 * 64];

    const int bh = blockIdx.x;
    const int j = 7 - (int)blockIdx.y;  // heavy chunks dispatched first
    const int tid = threadIdx.x;
    const int lane = tid & 63, wave = tid >> 6;
    const int ln = lane & 15, quad = lane >> 4;

    const bf16_t* Qb = Q + (size_t)bh * S_ * DK_;
    const bf16_t* Kb = K + (size_t)bh * S_ * DK_;
    const bf16_t* Vb = Vt + (size_t)bh * DK_ * S_;
    const int b = bh >> 4, h = bh & 15;

    bf16x8 ones8;
#pragma unroll
    for (int i = 0; i < 8; i++) ones8[i] = (bf16_t)1.0f;

    const int qb = j * 128;
    const int wq = qb + wave * 32;

    bf16x8 qf[2][2];
#pragma unroll
    for (int mi = 0; mi < 2; mi++)
#pragma unroll
        for (int kk = 0; kk < 2; kk++)
            qf[mi][kk] = *(const bf16x8*)(
                Qb + (size_t)(wq + mi * 16 + ln) * DK_ + kk * 32 + quad * 8);

    f32x4 o[2][4] = {};
    f32x4 ol[2] = {};

    // staging geometry: each gl_lds16 covers 8 rows x 64B
    const int r8 = lane >> 3;        // row-in-group 0..7
    const int sc = (lane & 7) ^ r8;  // pre-swizzled source chunk (key = row&7)

    const int kend = qb + 128;
    for (int kt = 0; kt < kend; kt += 64) {
        // ---- cooperative staging; K rows bit-shuffle-permuted at source ----
#pragma unroll
        for (int i = 0; i < 2; i++) {
            const int g = wave * 2 + i;  // 8-row group 0..7
            // LDS position p = g*8+r8 receives K row k(p):
            // k = g1*32 + g0*16 + r8_2*8 + g2*4 + (r8&3)
            const int krow = (g & 2) * 16 + (g & 1) * 16 + (r8 & 4) * 2 +
                             (g & 4) + (r8 & 3);
            gl_lds16(Kb + (size_t)(kt + krow) * DK_ + sc * 8, Ks + g * 512);
            gl_lds16(Vb + (size_t)(g * 8 + r8) * S_ + kt + sc * 8,
                     Vs + g * 512);
        }
        __syncthreads();

        if (kt <= wq + 31) {
            bf16x8 pa[2][2];  // [mi][kk] PV A-fragments, built in-register
#pragma unroll
            for (int mi = 0; mi < 2; mi++) {
                f32x4 s[4];
#pragma unroll
                for (int nt = 0; nt < 4; nt++) {
                    const bf16_t* kp = Ks + (nt * 16 + ln) * 64;
                    const bf16x8 kf0 =
                        *(const bf16x8*)(kp + ((quad ^ (ln & 7)) * 8));
                    const bf16x8 kf1 =
                        *(const bf16x8*)(kp + (((4 + quad) ^ (ln & 7)) * 8));
                    f32x4 a = {-16.f, -16.f, -16.f, -16.f};  // exp2 shift
                    a = mfma_bf16(kf0, qf[mi][0], a);  // swapped operands
                    a = mfma_bf16(kf1, qf[mi][1], a);
                    s[nt] = a;
                }
                const int q = wq + mi * 16 + ln;  // lane's q-row (global)
                const bool needmask = (kt + 63) > q;
#pragma unroll
                for (int nt = 0; nt < 4; nt++)
#pragma unroll
                    for (int r = 0; r < 4; r++) {
                        const int ktrue = kt + (nt & 1) * 32 + quad * 8 +
                                          (nt >> 1) * 4 + r;
                        float v = s[nt][r];
                        if (needmask && ktrue > q) v = NEGINF;
                        s[nt][r] = __builtin_amdgcn_exp2f(v);
                    }
                // pack: pa[kk] elem j=2w+e <- s[2*(w>>1)+kk][2*(w&1)+e]
#pragma unroll
                for (int kk = 0; kk < 2; kk++) {
                    bf16x8 t;
#pragma unroll
                    for (int w = 0; w < 4; w++) {
                        const int nts = 2 * (w >> 1) + kk;
                        const int r0 = 2 * (w & 1);
                        t[2 * w] = (bf16_t)s[nts][r0];
                        t[2 * w + 1] = (bf16_t)s[nts][r0 + 1];
                    }
                    pa[mi][kk] = t;
                }
                ol[mi] = mfma_bf16(pa[mi][0], ones8, ol[mi]);
                ol[mi] = mfma_bf16(pa[mi][1], ones8, ol[mi]);
            }
            // ---- P * V (V fragments from LDS, shared across mi) ----
#pragma unroll
            for (int dk = 0; dk < 4; dk++) {
                const bf16_t* vp = Vs + (dk * 16 + ln) * 64;
                const bf16x8 vf0 = *(const bf16x8*)(vp + ((quad ^ (ln & 7)) * 8));
                const bf16x8 vf1 =
                    *(const bf16x8*)(vp + (((4 + quad) ^ (ln & 7)) * 8));
#pragma unroll
                for (int mi = 0; mi < 2; mi++) {
                    o[mi][dk] = mfma_bf16(pa[mi][0], vf0, o[mi][dk]);
                    o[mi][dk] = mfma_bf16(pa[mi][1], vf1, o[mi][dk]);
                }
            }
        }
        __syncthreads();  // Ks/Vs reads done before next staging pass
    }

#pragma unroll
    for (int mi = 0; mi < 2; mi++)
#pragma unroll
        for (int r = 0; r < 4; r++) {
            const float inv = 1.f / ol[mi][r];
            const int row = wq + mi * 16 + quad * 4 + r;
            const size_t base = ((size_t)b * S_ + row) * D_ + h * DK_;
#pragma unroll
            for (int dk = 0; dk < 4; dk++)
                ctx[base + dk * 16 + ln] = (bf16_t)(o[mi][dk][r] * inv);
        }
}

// Vectorized d2d copy (16B per thread).
__global__ __launch_bounds__(256) void copy16(const f32x4* __restrict__ src,
                                              f32x4* __restrict__ dst, int n4) {
    const int i = blockIdx.x * 256 + threadIdx.x;
    if (i < n4) dst[i] = src[i];
}

extern "C" void kernel_launch(void* const* d_in, const int* in_sizes, int n_in,
                              void* d_out, int out_size, void* d_ws,
                              size_t ws_size, hipStream_t stream) {
    const float* query = (const float*)d_in[0];
    const float* key = (const float*)d_in[1];
    const float* value = (const float*)d_in[2];
    const float* w_q = (const float*)d_in[4];
    const float* b_q = (const float*)d_in[5];
    const float* w_k = (const float*)d_in[6];
    const float* b_k = (const float*)d_in[7];
    const float* w_v = (const float*)d_in[8];
    const float* b_v = (const float*)d_in[9];
    const float* w_o = (const float*)d_in[10];
    const float* b_o = (const float*)d_in[11];

    bf16_t* ws = (bf16_t*)d_ws;
    const size_t M8 = (size_t)M_ * D_;  // 8M elems
    const size_t DD = (size_t)D_ * D_;  // 1M elems
    bf16_t* Qw = ws;                    // [0, 8M) (Qw,Kw,Vw contiguous)
    bf16_t* Kw = ws + M8;
    bf16_t* Vw = ws + 2 * M8;
    bf16_t* wtq = ws + 3 * M8;          // 4 contiguous [D,D] bf16
    bf16_t* wtk = wtq + DD;
    bf16_t* wtv = wtk + DD;
    bf16_t* wto = wtv + DD;

    const int n8 = (int)(M8 / 8);
    const dim3 gg(M_ / 128, D_ / 128, 1);  // x=m-panel -> XCD owns 1/8 of A
    // Q scale folds 1/sqrt(DK) AND log2(e) for the exp2-domain softmax.
    const float qscale = 0.125f * 1.4426950408889634f;

    // big-ws path (>=120 MB): Xq/Xk/Xv + Cw in ws, 4 dispatches total.
    const size_t need_big = (7 * M8 + 4 * DD) * sizeof(bf16_t);  // 120 MB
    if (ws_size >= need_big) {
        bf16_t* Xq = ws + 3 * M8 + 4 * DD;  // Xq,Xk,Xv contiguous
        bf16_t* Cw = Xq + 3 * M8;
        float* Yw = (float*)d_out;

        prep<<<dim3(4096, 1, 7), 256, 0, stream>>>(
            w_q, w_k, w_v, w_o, wtq, query, key, value, Xq, n8);
        gemm_qkv<<<dim3(M_ / 128, D_ / 128, 3), 256, 0, stream>>>(
            Xq, wtq, b_q, b_k, b_v, Qw, qscale);

        MaskedMultiHeadAttention_90709709291709_kernel<<<dim3(B_ * H_, 8, 1),
                                                         256, 0, stream>>>(
            Qw, Kw, Vw, Cw);

        gemm_bt<0><<<gg, 256, 0, stream>>>(Cw, wto, b_o, Yw, 1.0f);
    } else {
        // fallback (ws < 120 MB): Xb parks in d_out, sequential cvts.
        bf16_t* Xb = (bf16_t*)d_out;
        const size_t need_direct = (4 * M8 + 4 * DD) * sizeof(bf16_t);
        const bool direct = ws_size >= need_direct;
        bf16_t* Cw = direct ? (ws + 3 * M8 + 4 * DD) : (bf16_t*)d_out;
        float* Yw = direct ? (float*)d_out : (float*)ws;
        const dim3 gc((n8 + 255) / 256, 1, 1);

        prep<<<dim3(1024, 1, 4), 256, 0, stream>>>(
            w_q, w_k, w_v, w_o, wtq, nullptr, nullptr, nullptr, nullptr, 0);
        cvt_bf16<<<gc, 256, 0, stream>>>(query, Xb, n8);
        gemm_bt<1><<<gg, 256, 0, stream>>>(Xb, wtq, b_q, Qw, qscale);
        cvt_bf16<<<gc, 256, 0, stream>>>(key, Xb, n8);
        gemm_bt<1><<<gg, 256, 0, stream>>>(Xb, wtk, b_k, Kw, 1.0f);
        cvt_bf16<<<gc, 256, 0, stream>>>(value, Xb, n8);
        gemm_bt<2><<<gg, 256, 0, stream>>>(Xb, wtv, b_v, Vw, 1.0f);

        MaskedMultiHeadAttention_90709709291709_kernel<<<dim3(B_ * H_, 8, 1),
                                                         256, 0, stream>>>(
            Qw, Kw, Vw, Cw);

        gemm_bt<0><<<gg, 256, 0, stream>>>(Cw, wto, b_o, Yw, 1.0f);
        if (!direct) {
            const int n4 = (int)((M8 * 4) / 16);
            copy16<<<dim3((n4 + 255) / 256), 256, 0, stream>>>(
                (const f32x4*)Yw, (f32x4*)d_out, n4);
        }
    }
}